// Round 5
// baseline (74.608 us; speedup 1.0000x reference)
//
#include <hip/hip_runtime.h>
#include <hip/hip_bf16.h>

// ---- problem constants ----
#define BATCH 16
#define CIN   12
#define HIMG  512
#define WIMG  512
#define OCH   768
#define KDIM  256            // 16*16 patch
#define HW    (HIMG*WIMG)    // 262144
#define NPATCH 1024          // 32*32 patches per batch

typedef __attribute__((ext_vector_type(8))) short short8;   // 8 bf16 = 4 VGPRs
typedef __attribute__((ext_vector_type(4))) float f32x4;

// ---------------------------------------------------------------------------
// Single fused kernel: channel-mean + patch-embedding GEMM, weights converted
// f32->bf16 in-register (no separate pack kernel, no stream serialization).
//
// One block = one (batch b, stripe is): 16 rows x 512 cols of the mean image,
// all 768 output channels.  512 threads = 8 waves; wave wv owns o-range
// [wv*96, wv*96+96) x 32 patches = 6x2 fragments of 16x16x32 bf16 MFMA.
//
// Phase 1 (staging): stream x (12 ch x 16 rows x 512 cols, each element read
//   exactly once grid-wide), channel-mean in regs, bf16 -> LDS patch tile
//   Bl[m = patch j][k = r*16+s].
// Phase 2 (MFMA): per k-step, load 6 weight fragments straight from the
//   f32 weight tensor (L2/L3-resident: 768 KB/block), cvt to bf16, MFMA.
// Cross-phase overlap comes from 2 resident blocks/CU (launch_bounds(512,4),
// VGPR<=128) — the m114 wave-level overlap that R4's explicit pipeline broke.
// ---------------------------------------------------------------------------
#define LDB 264   // 256 + 8 pad: row stride 528 B -> rows hit 2 lanes/bank (free)

__global__ __launch_bounds__(512, 4) void fused_kernel(
        const float* __restrict__ w,      // [OCH][KDIM] f32
        const float* __restrict__ x,      // [B][C][H][W]
        const float* __restrict__ bias,
        float* __restrict__ out) {        // [B][O][32][32]
    __shared__ short Bl[32][LDB];

    const int tid = threadIdx.x;
    const int b  = blockIdx.x >> 5;
    const int is = blockIdx.x & 31;       // stripe / patch-row index

    // ---- phase 1: channel mean -> LDS ----
    {
        const int col = (tid & 127) * 4;  // 0..508
        const int r0  = tid >> 7;         // 0..3
        const int j   = col >> 4;         // patch within stripe
        const int s0  = col & 15;
        const float* xb = x + (size_t)b * CIN * HW + (size_t)(is * 16) * WIMG + col;
        const float inv = 1.0f / 12.0f;
        #pragma unroll
        for (int p = 0; p < 4; ++p) {
            const int r = p * 4 + r0;
            const float* px = xb + (size_t)r * WIMG;
            float sx = 0.f, sy = 0.f, sz = 0.f, sw = 0.f;
            #pragma unroll
            for (int c = 0; c < CIN; ++c) {
                f32x4 v = *reinterpret_cast<const f32x4*>(px + (size_t)c * HW);
                sx += v.x; sy += v.y; sz += v.z; sw += v.w;
            }
            union { ushort4 u4; __hip_bfloat16 h[4]; } o;
            o.h[0] = __float2bfloat16(sx * inv);
            o.h[1] = __float2bfloat16(sy * inv);
            o.h[2] = __float2bfloat16(sz * inv);
            o.h[3] = __float2bfloat16(sw * inv);
            *reinterpret_cast<ushort4*>(&Bl[j][r * 16 + s0]) = o.u4;
        }
    }
    __syncthreads();

    // ---- phase 2: MFMA with in-register weight conversion ----
    const int lane = tid & 63;
    const int wv   = tid >> 6;           // 0..7
    const int lrow = lane & 15;
    const int lg   = lane >> 4;

    // lane's weight base: row (wv*96 + lrow), col (lg*8); fragment (fo,kk)
    // adds fo*16 rows and kk*32 cols.  Wave load = 16 rows x 128B segments.
    const float* wf = w + (size_t)(wv * 96 + lrow) * KDIM + lg * 8;

    f32x4 acc[6][2] = {};

    #pragma unroll
    for (int kk = 0; kk < 8; ++kk) {
        short8 af[6], bf[2];
        #pragma unroll
        for (int fo = 0; fo < 6; ++fo) {
            const float* src = wf + (size_t)(fo * 16) * KDIM + kk * 32;
            f32x4 a0 = *reinterpret_cast<const f32x4*>(src);
            f32x4 a1 = *reinterpret_cast<const f32x4*>(src + 4);
            union { short8 s; __hip_bfloat16 h[8]; } t;
            t.h[0] = __float2bfloat16(a0.x);
            t.h[1] = __float2bfloat16(a0.y);
            t.h[2] = __float2bfloat16(a0.z);
            t.h[3] = __float2bfloat16(a0.w);
            t.h[4] = __float2bfloat16(a1.x);
            t.h[5] = __float2bfloat16(a1.y);
            t.h[6] = __float2bfloat16(a1.z);
            t.h[7] = __float2bfloat16(a1.w);
            af[fo] = t.s;
        }
        #pragma unroll
        for (int fm = 0; fm < 2; ++fm)
            bf[fm] = *reinterpret_cast<const short8*>(&Bl[fm * 16 + lrow][kk * 32 + lg * 8]);
        #pragma unroll
        for (int fo = 0; fo < 6; ++fo)
            #pragma unroll
            for (int fm = 0; fm < 2; ++fm)
                acc[fo][fm] = __builtin_amdgcn_mfma_f32_16x16x32_bf16(af[fo], bf[fm], acc[fo][fm], 0, 0, 0);
    }

    // ---- epilogue: D row = o ((lane>>4)*4 + reg), col = m (lane&15) ----
    const int p0 = is * 32;
    float* ob = out + (size_t)b * OCH * NPATCH + p0;
    #pragma unroll
    for (int fo = 0; fo < 6; ++fo) {
        const int obase = wv * 96 + fo * 16 + lg * 4;
        #pragma unroll
        for (int r = 0; r < 4; ++r) {
            const int o = obase + r;
            const float bv = bias[o];
            float* orow = ob + (size_t)o * NPATCH;
            #pragma unroll
            for (int fm = 0; fm < 2; ++fm)
                orow[fm * 16 + lrow] = acc[fo][fm][r] + bv;
        }
    }
}

// ---------------------------------------------------------------------------
extern "C" void kernel_launch(void* const* d_in, const int* in_sizes, int n_in,
                              void* d_out, int out_size, void* d_ws, size_t ws_size,
                              hipStream_t stream) {
    const float* x    = (const float*)d_in[0];
    const float* w    = (const float*)d_in[1];
    const float* bias = (const float*)d_in[2];
    float* out = (float*)d_out;

    fused_kernel<<<BATCH * 32, 512, 0, stream>>>(w, x, bias, out);
}

// Round 6
// 54.230 us; speedup vs baseline: 1.3758x; 1.3758x over previous
//
#include <hip/hip_runtime.h>
#include <hip/hip_bf16.h>

// ---- problem constants ----
#define BATCH 16
#define CIN   12
#define HIMG  512
#define WIMG  512
#define OCH   768
#define KDIM  256            // 16*16 patch
#define HW    (HIMG*WIMG)    // 262144
#define NPATCH 1024          // 32*32 patches per batch

#define MEAN_BLOCKS 4096     // BATCH*HW/4/256
#define PACK_BLOCKS 96       // OCH*KDIM/(256*8)... 24576 u / 256 = 96

typedef __attribute__((ext_vector_type(8))) short short8;   // 8 bf16 = 4 VGPRs
typedef __attribute__((ext_vector_type(4))) float f32x4;

// ---------------------------------------------------------------------------
// Kernel A (merged): channel-mean (blocks 0..4095) + weight pack (4096..4191).
//
// mean: xm[b][h][w] = mean_c x[b][c][h][w], f32 -> bf16.  Each thread: one
//   float4 position, 12 strided channel loads (48 loads in flight), 8 resident
//   blocks/CU -> deep MLP, throughput-bound (validated structure from R1).
// pack: w f32 -> bf16 in MFMA fragment-lane order:
//   packed[u][0..7], u = (ot*8 + kk)*64 + lane holds
//   w[ot*16 + (lane&15)][kk*32 + (lane>>4)*8 + j], j=0..7.
// ---------------------------------------------------------------------------
__global__ __launch_bounds__(256) void mean_pack_kernel(
        const float* __restrict__ x, __hip_bfloat16* __restrict__ xm,
        const float* __restrict__ w, short8* __restrict__ wbp) {
    const int bid = blockIdx.x;
    if (bid < MEAN_BLOCKS) {
        int idx = bid * 256 + threadIdx.x;              // float4 index
        int b = idx >> 16;                              // 65536 float4 per image
        int pos = (idx & 65535) << 2;
        const float* px = x + (size_t)b * CIN * HW + pos;
        float sx = 0.f, sy = 0.f, sz = 0.f, sw = 0.f;
        #pragma unroll
        for (int c = 0; c < CIN; ++c) {
            f32x4 v = *reinterpret_cast<const f32x4*>(px + (size_t)c * HW);
            sx += v.x; sy += v.y; sz += v.z; sw += v.w;
        }
        const float inv = 1.0f / 12.0f;
        union { ushort4 u4; __hip_bfloat16 h[4]; } o;
        o.h[0] = __float2bfloat16(sx * inv);
        o.h[1] = __float2bfloat16(sy * inv);
        o.h[2] = __float2bfloat16(sz * inv);
        o.h[3] = __float2bfloat16(sw * inv);
        *reinterpret_cast<ushort4*>(xm + (size_t)idx * 4) = o.u4;
    } else {
        int u = (bid - MEAN_BLOCKS) * 256 + threadIdx.x;   // 0..24575
        int lane = u & 63;
        int kk   = (u >> 6) & 7;
        int ot   = u >> 9;                                 // 0..47
        int o = ot * 16 + (lane & 15);
        int k = kk * 32 + (lane >> 4) * 8;
        const float* src = w + (size_t)o * KDIM + k;
        f32x4 v0 = *reinterpret_cast<const f32x4*>(src);
        f32x4 v1 = *reinterpret_cast<const f32x4*>(src + 4);
        union { short8 s; __hip_bfloat16 h[8]; } t;
        t.h[0] = __float2bfloat16(v0.x);
        t.h[1] = __float2bfloat16(v0.y);
        t.h[2] = __float2bfloat16(v0.z);
        t.h[3] = __float2bfloat16(v0.w);
        t.h[4] = __float2bfloat16(v1.x);
        t.h[5] = __float2bfloat16(v1.y);
        t.h[6] = __float2bfloat16(v1.z);
        t.h[7] = __float2bfloat16(v1.w);
        wbp[u] = t.s;
    }
}

// ---------------------------------------------------------------------------
// Kernel B: fat-block patch-embedding GEMM.
// One block = one (batch b, stripe is): 32 patches, all 768 o-channels.
// 512 threads = 8 waves; wave wv owns o-range [wv*96, wv*96+96) x 32 patches
// = 6x2 fragments of 16x16x32 bf16 MFMA, K = 256 in 8 steps.
// Phase 1: copy the 16 KB bf16 stripe of xm into LDS patch-major tile
//   Bl[m = patch j][k = r*16+s]  (L2/L3-resident read, 2 short8 per thread).
// Phase 2: A-fragments stream from packed weights (L2-resident, coalesced
//   1 KiB wave loads), B-fragments from LDS, accumulate in AGPRs.
// Write-bound: 98 KB out per block, 50 MB total.
// ---------------------------------------------------------------------------
#define LDB 264   // 256 + 8 pad

__global__ __launch_bounds__(512, 4) void gemm_kernel(
        const short8* __restrict__ wbp,          // packed weights
        const __hip_bfloat16* __restrict__ xm,   // [B][H][W] mean image
        const float* __restrict__ bias,
        float* __restrict__ out) {               // [B][O][32][32]
    __shared__ short Bl[32][LDB];

    const int tid = threadIdx.x;
    const int b  = blockIdx.x >> 5;
    const int is = blockIdx.x & 31;       // stripe / patch-row index

    // ---- phase 1: 16 rows x 512 cols bf16 -> LDS ----
    {
        const int r = tid >> 5;           // 0..15
        const int j = tid & 31;           // patch within stripe
        const short* src = reinterpret_cast<const short*>(
            xm + (size_t)b * HW + (size_t)(is * 16 + r) * WIMG + j * 16);
        *reinterpret_cast<short8*>(&Bl[j][r * 16])     = *reinterpret_cast<const short8*>(src);
        *reinterpret_cast<short8*>(&Bl[j][r * 16 + 8]) = *reinterpret_cast<const short8*>(src + 8);
    }
    __syncthreads();

    // ---- phase 2: MFMA ----
    const int lane = tid & 63;
    const int wv   = tid >> 6;           // 0..7
    const int lrow = lane & 15;
    const int lg   = lane >> 4;

    f32x4 acc[6][2] = {};
    const short8* wp = wbp + (size_t)(wv * 6) * 8 * 64 + lane;  // fo=0,kk=0 base

    #pragma unroll
    for (int kk = 0; kk < 8; ++kk) {
        short8 af[6], bf[2];
        #pragma unroll
        for (int fo = 0; fo < 6; ++fo)
            af[fo] = wp[(size_t)(fo * 8 + kk) * 64];
        #pragma unroll
        for (int fm = 0; fm < 2; ++fm)
            bf[fm] = *reinterpret_cast<const short8*>(&Bl[fm * 16 + lrow][kk * 32 + lg * 8]);
        #pragma unroll
        for (int fo = 0; fo < 6; ++fo)
            #pragma unroll
            for (int fm = 0; fm < 2; ++fm)
                acc[fo][fm] = __builtin_amdgcn_mfma_f32_16x16x32_bf16(af[fo], bf[fm], acc[fo][fm], 0, 0, 0);
    }

    // ---- epilogue: D row = o ((lane>>4)*4 + reg), col = m (lane&15) ----
    const int p0 = is * 32;
    float* ob = out + (size_t)b * OCH * NPATCH + p0;
    #pragma unroll
    for (int fo = 0; fo < 6; ++fo) {
        const int obase = wv * 96 + fo * 16 + lg * 4;
        #pragma unroll
        for (int r = 0; r < 4; ++r) {
            const int o = obase + r;
            const float bv = bias[o];
            float* orow = ob + (size_t)o * NPATCH;
            #pragma unroll
            for (int fm = 0; fm < 2; ++fm)
                orow[fm * 16 + lrow] = acc[fo][fm][r] + bv;
        }
    }
}

// ---------------------------------------------------------------------------
extern "C" void kernel_launch(void* const* d_in, const int* in_sizes, int n_in,
                              void* d_out, int out_size, void* d_ws, size_t ws_size,
                              hipStream_t stream) {
    const float* x    = (const float*)d_in[0];
    const float* w    = (const float*)d_in[1];
    const float* bias = (const float*)d_in[2];
    float* out = (float*)d_out;

    __hip_bfloat16* xm = (__hip_bfloat16*)d_ws;                                   // 8 MiB
    short8* wbp = (short8*)((char*)d_ws + (size_t)BATCH * HW * 2);                // 384 KiB

    mean_pack_kernel<<<MEAN_BLOCKS + PACK_BLOCKS, 256, 0, stream>>>(x, xm, w, wbp);
    gemm_kernel<<<BATCH * 32, 512, 0, stream>>>(wbp, xm, bias, out);
}